// Round 1
// 329.355 us; speedup vs baseline: 1.4152x; 1.4152x over previous
//
#include <hip/hip_runtime.h>
#include <cfloat>

// Problem constants (fixed by the reference):
//   inputs  [8,2048,1024] fp32 -> flat [N=16384, H=4, dh=256]
//   codebook[H=4, K=1024, dh=256] fp32
//   out[0] = loss, out[1..] = quantized (16777216 floats)
#define NH    4
#define NK    1024
#define DHD   256
#define NTOK  16384
#define ROWS  (NH * DHD)   // 1024 floats per token row

typedef __attribute__((ext_vector_type(8))) short bf16x8;
typedef __attribute__((ext_vector_type(4))) float f32x4;

// ---------------------------------------------------------------------------
// Workspace layout (bytes). Fast path needs ~4.2 MB; else fp32 fallback.
// (cvt_x eliminated: A-fragments are built in-kernel from fp32 x directly.)
// ---------------------------------------------------------------------------
#define WS_CSQ  ((size_t)0)
#define WS_BH   ((size_t)16384)                    // cb hi: 4*8*4*1024*16 = 2 MB
#define WS_BL   (WS_BH + (size_t)2097152)          // cb lo: 2 MB
#define WS_NEED (WS_BL + (size_t)2097152)

// ---------------------------------------------------------------------------
// bf16 split helpers (round-to-nearest-even)
// ---------------------------------------------------------------------------
__device__ __forceinline__ unsigned short f32_to_bf16_rn(float f) {
    unsigned u = __float_as_uint(f);
    u += 0x7FFFu + ((u >> 16) & 1u);
    return (unsigned short)(u >> 16);
}
__device__ __forceinline__ float bf16_as_f32(unsigned short h) {
    return __uint_as_float(((unsigned)h) << 16);
}

// direct global->LDS DMA, 16B per lane, dest = wave-uniform base + lane*16
__device__ __forceinline__ void gload_lds16(const uint4* g, uint4* l) {
    __builtin_amdgcn_global_load_lds(
        (const __attribute__((address_space(1))) void*)g,
        (__attribute__((address_space(3))) void*)l, 16, 0, 0);
}

// ---------------------------------------------------------------------------
// Kernel 0: per-code squared norms csq[h*NK + k] = sum_d cb[h][k][d]^2 (fp32)
// ---------------------------------------------------------------------------
__global__ __launch_bounds__(64) void csq_kernel(const float* __restrict__ cb,
                                                 float* __restrict__ csq) {
    const int code = blockIdx.x;                 // 0 .. NH*NK-1
    const int lane = threadIdx.x;
    const float4 v = *(const float4*)(cb + (size_t)code * DHD + lane * 4);
    float s = v.x * v.x + v.y * v.y + v.z * v.z + v.w * v.w;
#pragma unroll
    for (int off = 32; off > 0; off >>= 1) s += __shfl_down(s, off, 64);
    if (lane == 0) csq[code] = s;
}

// ---------------------------------------------------------------------------
// cvt_cb: codebook fp32 -> hi/lo bf16, swizzled [h][dc][kk][code] 16B units
// Block 256 threads = 8 codes.
// ---------------------------------------------------------------------------
__global__ __launch_bounds__(256) void cvt_cb_kernel(const float* __restrict__ cb,
                                                     uint4* __restrict__ bch,
                                                     uint4* __restrict__ bcl) {
    const int g = blockIdx.x * 8 + (threadIdx.x >> 5);   // 0..4095
    const int o = threadIdx.x & 31;                      // dh-octet
    const float* src = cb + (size_t)g * DHD + o * 8;
    unsigned wh[4], wl[4];
#pragma unroll
    for (int i = 0; i < 4; ++i) {
        const float f0 = src[2 * i], f1 = src[2 * i + 1];
        const unsigned short h0 = f32_to_bf16_rn(f0);
        const unsigned short h1 = f32_to_bf16_rn(f1);
        const unsigned short l0 = f32_to_bf16_rn(f0 - bf16_as_f32(h0));
        const unsigned short l1 = f32_to_bf16_rn(f1 - bf16_as_f32(h1));
        wh[i] = (unsigned)h0 | ((unsigned)h1 << 16);
        wl[i] = (unsigned)l0 | ((unsigned)l1 << 16);
    }
    const int hh = g >> 10, c = g & 1023, dc = o >> 2, kk = o & 3;
    const size_t unit = (size_t)((hh * 8 + dc) * 4 + kk) * NK + c;
    bch[unit] = make_uint4(wh[0], wh[1], wh[2], wh[3]);
    bcl[unit] = make_uint4(wl[0], wl[1], wl[2], wl[3]);
}

// first-index "less" for (value, index) pairs
__device__ __forceinline__ bool lt_vi(float v, int i, float w, int j) {
    return (v < w) || (v == w && i < j);
}

// ---------------------------------------------------------------------------
// Bit-exact replica of numpy's pairwise sum of squares for n=256 (VERIFIED R5)
// ---------------------------------------------------------------------------
__device__ __forceinline__ float np_sq_pairwise256(const float* __restrict__ a) {
#pragma clang fp contract(off)
    float tot = 0.f;
#pragma unroll
    for (int blk = 0; blk < 2; ++blk) {
        const float* p = a + blk * 128;
        float r0 = p[0] * p[0], r1 = p[1] * p[1], r2 = p[2] * p[2], r3 = p[3] * p[3];
        float r4 = p[4] * p[4], r5 = p[5] * p[5], r6 = p[6] * p[6], r7 = p[7] * p[7];
#pragma clang loop unroll_count(2)
        for (int i = 8; i < 128; i += 8) {
            r0 = r0 + p[i + 0] * p[i + 0];
            r1 = r1 + p[i + 1] * p[i + 1];
            r2 = r2 + p[i + 2] * p[i + 2];
            r3 = r3 + p[i + 3] * p[i + 3];
            r4 = r4 + p[i + 4] * p[i + 4];
            r5 = r5 + p[i + 5] * p[i + 5];
            r6 = r6 + p[i + 6] * p[i + 6];
            r7 = r7 + p[i + 7] * p[i + 7];
        }
        const float res = ((r0 + r1) + (r2 + r3)) + ((r4 + r5) + (r6 + r7));
        tot = (blk == 0) ? res : (tot + res);
    }
    return tot;
}

// Bit-exact replica of np.einsum's sequential fp32 mul+add loop (VERIFIED R5).
__device__ __forceinline__ float np_dot_seq256(const float* __restrict__ a,
                                               const float* __restrict__ b) {
#pragma clang fp contract(off)
    float s = 0.f;
#pragma clang loop unroll_count(4)
    for (int i = 0; i < 256; ++i) s = s + a[i] * b[i];
    return s;
}

// ===========================================================================
// FAST PATH: split-bf16 MFMA kernel.
// Grid (NTOK/128, NH), 256 threads / 4 waves. Wave w: tokens w*32..w*32+31
// (2 MFMA row-tiles of 16). Codes looped in 64-wide tiles (4 col-tiles).
// dot = hi*hi + hi*lo + lo*hi via mfma_f32_16x16x32_bf16; A token-stationary
// in registers (converted in-kernel from fp32 x, bit-exact vs old cvt_x);
// B staged in LDS per 64-code tile via global_load_lds (direct DMA).
// Layouts (doc-verified): A-frag A[m=lane&15][k=(lane>>4)*8+j];
// B-frag (B^T input [code][dh]): B[n=lane&15][k=(lane>>4)*8+j];
// C/D: col(n)=lane&15, row(m)=(lane>>4)*4+reg.
// ===========================================================================
__global__ __launch_bounds__(256, 2) void vq_mfma(const float* __restrict__ x,
                                                  const float* __restrict__ cb,
                                                  const float* __restrict__ csq,
                                                  const uint4* __restrict__ bch,
                                                  const uint4* __restrict__ bcl,
                                                  float* __restrict__ out) {
    __shared__ uint4 BsH[2048];    // 64 codes x 256 dh (hi) as [dcKK(32)][code(64)]
    __shared__ uint4 BsL[2048];    // lo
    __shared__ float Cs[NK];       // per-head code norms, loaded once
    __shared__ int   Cand[128][2];
    __shared__ int   SIdx[128];
    __shared__ float WSum[4];

    const int tid  = threadIdx.x;
    const int h    = blockIdx.y;
    const int t0   = blockIdx.x * 128;
    const int wv   = tid >> 6;
    const int lane = tid & 63;
    const int kk   = lane >> 4;    // 0..3 (k-octet)
    const int ln   = lane & 15;

    const float* xh  = x  + (size_t)t0 * ROWS + h * DHD;
    const float* cbh = cb + (size_t)h * NK * DHD;

    // Code norms: whole head once (removes per-k0-iteration Cs producer).
#pragma unroll
    for (int i = tid; i < NK; i += 256) Cs[i] = csq[h * NK + i];

    // A fragments: token-stationary, whole dh in registers (hi+lo),
    // converted in-registers from fp32 x (bit-exact same split as cvt_x).
    bf16x8 aH[2][8], aL[2][8];
    {
        const int tokb = t0 + wv * 32 + ln;
        const float* xa = x + (size_t)tokb * ROWS + h * DHD + kk * 8;
#pragma unroll
        for (int rt = 0; rt < 2; ++rt) {
#pragma unroll
            for (int dc = 0; dc < 8; ++dc) {
                const float* p = xa + (size_t)(rt * 16) * ROWS + dc * 32;
                const float4 f0 = *(const float4*)p;
                const float4 f1 = *(const float4*)(p + 4);
                const float f[8] = {f0.x, f0.y, f0.z, f0.w, f1.x, f1.y, f1.z, f1.w};
                bf16x8 hv, lv;
#pragma unroll
                for (int j = 0; j < 8; ++j) {
                    const unsigned short hb = f32_to_bf16_rn(f[j]);
                    hv[j] = (short)hb;
                    lv[j] = (short)f32_to_bf16_rn(f[j] - bf16_as_f32(hb));
                }
                aH[rt][dc] = hv;
                aL[rt][dc] = lv;
            }
        }
    }

    float b1[8], b2[8];
    int   i1[8], i2[8];
#pragma unroll
    for (int s = 0; s < 8; ++s) { b1[s] = FLT_MAX; b2[s] = FLT_MAX; i1[s] = 0; i2[s] = 0; }

    for (int k0 = 0; k0 < NK; k0 += 64) {
        __syncthreads();  // protect Bs from previous-iteration readers (also orders Cs)
        // stage B tile: 2048 hi + 2048 lo units via direct global->LDS DMA.
        // Wave wv, chunk p: LDS elements [p*256+wv*64 .. +63] <- bch[(h*32+p*4+wv)*NK+k0 + lane]
#pragma unroll
        for (int p = 0; p < 8; ++p) {
            const size_t w = (size_t)(h * 32 + p * 4 + wv) * NK + k0 + lane;
            gload_lds16(&bch[w], &BsH[p * 256 + wv * 64]);
            gload_lds16(&bcl[w], &BsL[p * 256 + wv * 64]);
        }
        __syncthreads();  // drains vmcnt(0): DMA'd tile visible

        f32x4 acc[2][4];
#pragma unroll
        for (int rt = 0; rt < 2; ++rt)
#pragma unroll
            for (int ct = 0; ct < 4; ++ct) acc[rt][ct] = (f32x4){0.f, 0.f, 0.f, 0.f};

#pragma unroll
        for (int dc = 0; dc < 8; ++dc) {
#pragma unroll
            for (int ct = 0; ct < 4; ++ct) {
                const int bu = (dc * 4 + kk) * 64 + ct * 16 + ln;
                const bf16x8 bH = *(const bf16x8*)&BsH[bu];
                const bf16x8 bL = *(const bf16x8*)&BsL[bu];
#pragma unroll
                for (int rt = 0; rt < 2; ++rt) {
                    acc[rt][ct] = __builtin_amdgcn_mfma_f32_16x16x32_bf16(aH[rt][dc], bH, acc[rt][ct], 0, 0, 0);
                    acc[rt][ct] = __builtin_amdgcn_mfma_f32_16x16x32_bf16(aH[rt][dc], bL, acc[rt][ct], 0, 0, 0);
                    acc[rt][ct] = __builtin_amdgcn_mfma_f32_16x16x32_bf16(aL[rt][dc], bH, acc[rt][ct], 0, 0, 0);
                }
            }
        }

        // distances (x_sq dropped: per-token constant) + running top-2
#pragma unroll
        for (int rt = 0; rt < 2; ++rt)
#pragma unroll
            for (int ct = 0; ct < 4; ++ct) {
                const float cs   = Cs[k0 + ct * 16 + ln];
                const int   codg = k0 + ct * 16 + ln;
#pragma unroll
                for (int r = 0; r < 4; ++r) {
                    const float dist = cs - 2.f * acc[rt][ct][r];
                    const int   s    = rt * 4 + r;
                    if (dist < b1[s]) { b2[s] = b1[s]; i2[s] = i1[s]; b1[s] = dist; i1[s] = codg; }
                    else if (dist < b2[s]) { b2[s] = dist; i2[s] = codg; }
                }
            }
    }

    // Merge top-2 across the 16 lanes sharing each token (xor bits 0..3).
#pragma unroll
    for (int s = 0; s < 8; ++s) {
        float v1 = b1[s], v2 = b2[s];
        int   j1 = i1[s], j2 = i2[s];
#pragma unroll
        for (int m = 1; m <= 8; m <<= 1) {
            const float o1 = __shfl_xor(v1, m, 64);
            const int   oj1 = __shfl_xor(j1, m, 64);
            const float o2 = __shfl_xor(v2, m, 64);
            const int   oj2 = __shfl_xor(j2, m, 64);
            if (lt_vi(o1, oj1, v1, j1)) {
                if (lt_vi(v1, j1, o2, oj2)) { v2 = v1; j2 = j1; }
                else                        { v2 = o2; j2 = oj2; }
                v1 = o1; j1 = oj1;
            } else if (lt_vi(o1, oj1, v2, j2)) {
                v2 = o1; j2 = oj1;
            }
        }
        if (ln == 0) {
            const int tl = wv * 32 + (s >> 2) * 16 + kk * 4 + (s & 3);
            Cand[tl][0] = j1;
            Cand[tl][1] = j2;
        }
    }
    __syncthreads();

    // Refinement: bit-exact numpy emulation on 2 candidates (VERIFIED R5/R6).
    {
        const int token = tid >> 1;          // 0..127
        const int cand  = tid & 1;
        const int code  = Cand[token][cand];
        const float* xr = xh + (size_t)token * ROWS;
        const float* cr = cbh + (size_t)code * DHD;
        const float X = np_sq_pairwise256(xr);
        const float C = np_sq_pairwise256(cr);
        const float D = np_dot_seq256(xr, cr);
        float d;
        {
#pragma clang fp contract(off)
            const float t = X + C;
            d = t - 2.0f * D;
        }
        const float od = __shfl_xor(d, 1, 64);
        if (cand == 0) {
            const int jA = code;
            const int jB = Cand[token][1];
            const bool pickB = (od < d) || (od == d && jB < jA);
            SIdx[token] = pickB ? jB : jA;
        }
    }
    __syncthreads();

    // Epilogue: gather codebook rows -> out (float4), accumulate (q-x)^2.
    float lacc = 0.f;
    for (int t = wv; t < 128; t += 4) {
        const float4 q4 = *(const float4*)(cbh + (size_t)SIdx[t] * DHD + (lane << 2));
        const float4 x4 = *(const float4*)(xh + (size_t)t * ROWS + (lane << 2));
        const float dx = q4.x - x4.x, dy = q4.y - x4.y;
        const float dz = q4.z - x4.z, dw = q4.w - x4.w;
        lacc += dx * dx + dy * dy + dz * dz + dw * dw;
        *(float4*)(out + 1 + (size_t)(t0 + t) * ROWS + h * DHD + (lane << 2)) = q4;
    }
#pragma unroll
    for (int off = 32; off > 0; off >>= 1) lacc += __shfl_down(lacc, off, 64);
    if (lane == 0) WSum[wv] = lacc;
    __syncthreads();
    if (tid == 0) {
        const float s = WSum[0] + WSum[1] + WSum[2] + WSum[3];
        atomicAdd(out, s * (0.25f / 16777216.f));  // 0.25 * mean
    }
}

// ===========================================================================
// FALLBACK (ws too small): R6 fp32 kernel — verified passing at 558 us.
// ===========================================================================
#define TN 128
#define TK 128
#define KC 16
#define APAD 4
#define BPAD 4

__global__ __launch_bounds__(256, 2) void vq_main_fp32(const float* __restrict__ x,
                                                       const float* __restrict__ cb,
                                                       const float* __restrict__ csq,
                                                       float* __restrict__ out) {
    __shared__ float As[KC][TN + APAD];
    __shared__ float Bs[KC][TK + BPAD];
    __shared__ float Cs[TK];
    __shared__ int   Cand[TN][2];
    __shared__ int   SIdx[TN];
    __shared__ float WSum[4];

    const int tid = threadIdx.x;
    const int h   = blockIdx.y;
    const int t0  = blockIdx.x * TN;
    const int ty  = tid >> 4;
    const int tx  = tid & 15;

    const float* xh  = x  + (size_t)t0 * ROWS + h * DHD;
    const float* cbh = cb + (size_t)h * NK * DHD;

    const int sr = tid >> 1;
    const int sd = (tid & 1) << 3;

    float b1[8], b2[8];
    int   i1[8], i2[8];
#pragma unroll
    for (int r = 0; r < 8; ++r) { b1[r] = FLT_MAX; b2[r] = FLT_MAX; i1[r] = 0; i2[r] = 0; }

    for (int k0 = 0; k0 < NK; k0 += TK) {
        __syncthreads();
        if (tid < TK) Cs[tid] = csq[h * NK + k0 + tid];

        float acc[8][8];
#pragma unroll
        for (int r = 0; r < 8; ++r)
#pragma unroll
            for (int c = 0; c < 8; ++c) acc[r][c] = 0.f;

        for (int d0 = 0; d0 < DHD; d0 += KC) {
            __syncthreads();
            {
                const float* ap = xh + (size_t)sr * ROWS + d0 + sd;
                const float4 a0 = *(const float4*)ap;
                const float4 a1 = *(const float4*)(ap + 4);
                As[sd + 0][sr] = a0.x; As[sd + 1][sr] = a0.y;
                As[sd + 2][sr] = a0.z; As[sd + 3][sr] = a0.w;
                As[sd + 4][sr] = a1.x; As[sd + 5][sr] = a1.y;
                As[sd + 6][sr] = a1.z; As[sd + 7][sr] = a1.w;
            }
            {
                const float* bp = cbh + (size_t)(k0 + sr) * DHD + d0 + sd;
                const float4 b0v = *(const float4*)bp;
                const float4 b1v = *(const float4*)(bp + 4);
                Bs[sd + 0][sr] = b0v.x; Bs[sd + 1][sr] = b0v.y;
                Bs[sd + 2][sr] = b0v.z; Bs[sd + 3][sr] = b0v.w;
                Bs[sd + 4][sr] = b1v.x; Bs[sd + 5][sr] = b1v.y;
                Bs[sd + 6][sr] = b1v.z; Bs[sd + 7][sr] = b1v.w;
            }
            __syncthreads();
#pragma unroll 4
            for (int kc = 0; kc < KC; ++kc) {
                const float4 a0 = *(const float4*)&As[kc][ty << 3];
                const float4 a1 = *(const float4*)&As[kc][(ty << 3) + 4];
                const float4 p0 = *(const float4*)&Bs[kc][tx << 2];
                const float4 p1 = *(const float4*)&Bs[kc][64 + (tx << 2)];
                const float aa[8] = {a0.x, a0.y, a0.z, a0.w, a1.x, a1.y, a1.z, a1.w};
                const float bb[8] = {p0.x, p0.y, p0.z, p0.w, p1.x, p1.y, p1.z, p1.w};
#pragma unroll
                for (int r = 0; r < 8; ++r)
#pragma unroll
                    for (int c = 0; c < 8; ++c)
                        acc[r][c] = fmaf(aa[r], bb[c], acc[r][c]);
            }
        }
#pragma unroll
        for (int r = 0; r < 8; ++r) {
#pragma unroll
            for (int c = 0; c < 8; ++c) {
                const int cc = (c < 4) ? ((tx << 2) + c) : (64 + (tx << 2) + c - 4);
                const float dist = Cs[cc] - 2.f * acc[r][c];
                const int   idx  = k0 + cc;
                if (dist < b1[r]) { b2[r] = b1[r]; i2[r] = i1[r]; b1[r] = dist; i1[r] = idx; }
                else if (dist < b2[r]) { b2[r] = dist; i2[r] = idx; }
            }
        }
    }

#pragma unroll
    for (int r = 0; r < 8; ++r) {
        float v1 = b1[r], v2 = b2[r];
        int   j1 = i1[r], j2 = i2[r];
#pragma unroll
        for (int m = 1; m <= 8; m <<= 1) {
            const float o1 = __shfl_xor(v1, m, 64);
            const int   oj1 = __shfl_xor(j1, m, 64);
            const float o2 = __shfl_xor(v2, m, 64);
            const int   oj2 = __shfl_xor(j2, m, 64);
            if (lt_vi(o1, oj1, v1, j1)) {
                if (lt_vi(v1, j1, o2, oj2)) { v2 = v1; j2 = j1; }
                else                        { v2 = o2; j2 = oj2; }
                v1 = o1; j1 = oj1;
            } else if (lt_vi(o1, oj1, v2, j2)) {
                v2 = o1; j2 = oj1;
            }
        }
        b1[r] = v1; i1[r] = j1; b2[r] = v2; i2[r] = j2;
    }
    if (tx == 0) {
#pragma unroll
        for (int r = 0; r < 8; ++r) {
            Cand[(ty << 3) + r][0] = i1[r];
            Cand[(ty << 3) + r][1] = i2[r];
        }
    }
    __syncthreads();

    {
        const int token = tid >> 1;
        const int cand  = tid & 1;
        const int code  = Cand[token][cand];
        const float* xr = xh + (size_t)token * ROWS;
        const float* cr = cbh + (size_t)code * DHD;
        const float X = np_sq_pairwise256(xr);
        const float C = np_sq_pairwise256(cr);
        const float D = np_dot_seq256(xr, cr);
        float d;
        {
#pragma clang fp contract(off)
            const float t = X + C;
            d = t - 2.0f * D;
        }
        const float od = __shfl_xor(d, 1, 64);
        if (cand == 0) {
            const int jA = code;
            const int jB = Cand[token][1];
            const bool pickB = (od < d) || (od == d && jB < jA);
            SIdx[token] = pickB ? jB : jA;
        }
    }
    __syncthreads();

    const int wav  = tid >> 6;
    const int lane = tid & 63;
    float lacc = 0.f;
    for (int t = wav; t < TN; t += 4) {
        const float4 q4 = *(const float4*)(cbh + (size_t)SIdx[t] * DHD + (lane << 2));
        const float4 x4 = *(const float4*)(xh + (size_t)t * ROWS + (lane << 2));
        const float dx = q4.x - x4.x, dy = q4.y - x4.y;
        const float dz = q4.z - x4.z, dw = q4.w - x4.w;
        lacc += dx * dx + dy * dy + dz * dz + dw * dw;
        *(float4*)(out + 1 + (size_t)(t0 + t) * ROWS + h * DHD + (lane << 2)) = q4;
    }
#pragma unroll
    for (int off = 32; off > 0; off >>= 1) lacc += __shfl_down(lacc, off, 64);
    if (lane == 0) WSum[wav] = lacc;
    __syncthreads();
    if (tid == 0) {
        const float s = WSum[0] + WSum[1] + WSum[2] + WSum[3];
        atomicAdd(out, s * (0.25f / 16777216.f));
    }
}

extern "C" void kernel_launch(void* const* d_in, const int* in_sizes, int n_in,
                              void* d_out, int out_size, void* d_ws, size_t ws_size,
                              hipStream_t stream) {
    const float* x   = (const float*)d_in[0];   // inputs  [16777216]
    const float* cb  = (const float*)d_in[1];   // codebook [1048576]
    float*       out = (float*)d_out;           // [1 + 16777216]
    char*        ws  = (char*)d_ws;
    float*       csq = (float*)(ws + WS_CSQ);

    hipMemsetAsync(d_out, 0, sizeof(float), stream);
    csq_kernel<<<NH * NK, 64, 0, stream>>>(cb, csq);

    if (ws_size >= WS_NEED) {
        uint4* bch = (uint4*)(ws + WS_BH);
        uint4* bcl = (uint4*)(ws + WS_BL);
        cvt_cb_kernel<<<NH * NK / 8, 256, 0, stream>>>(cb, bch, bcl);
        dim3 grid(NTOK / 128, NH);
        vq_mfma<<<grid, 256, 0, stream>>>(x, cb, csq, bch, bcl, out);
    } else {
        dim3 grid(NTOK / TN, NH);
        vq_main_fp32<<<grid, 256, 0, stream>>>(x, cb, csq, out);
    }
}